// Round 1
// baseline (333.514 us; speedup 1.0000x reference)
//
#include <hip/hip_runtime.h>
#include <math.h>

#define DIM 1024
#define NE 4
#define NTOK 4096
#define NB 8
#define CAP 1024   // floor(0.25 * 4096)

// ---------------------------------------------------------------------------
// init: mask = -1, sel = 0  (ws is poisoned 0xAA before every timed call)
// ---------------------------------------------------------------------------
__global__ __launch_bounds__(256) void init_kernel(int* __restrict__ mask,
                                                   int* __restrict__ sel) {
    int i = blockIdx.x * 256 + threadIdx.x;
    if (i < NTOK) { mask[i] = -1; sel[i] = 0; }
}

// ---------------------------------------------------------------------------
// probs: one wave per token. logits in double (correctly-rounded fp32), then
// softmax in double, rounded once to fp32. probs layout: [(b*N+n)*4 + e]
// ---------------------------------------------------------------------------
__global__ __launch_bounds__(256) void probs_kernel(const float* __restrict__ tokens,
                                                    const float* __restrict__ W,
                                                    const float* __restrict__ bias,
                                                    float* __restrict__ probs) {
    __shared__ float4 Wl[NE * 256];   // W[e][d] as float4 chunks, 16 KB
    int tid = threadIdx.x;
    const float4* W4 = (const float4*)W;
    for (int i = tid; i < NE * 256; i += 256) Wl[i] = W4[i];
    __syncthreads();

    int wave = tid >> 6, lane = tid & 63;
    long tok = (long)blockIdx.x * 4 + wave;            // 0 .. 32767
    const float4* t4 = (const float4*)(tokens + tok * DIM);

    double a0 = 0, a1 = 0, a2 = 0, a3 = 0;
#pragma unroll
    for (int kk = 0; kk < 4; kk++) {
        int c = lane + 64 * kk;                         // coalesced float4
        float4 v  = t4[c];
        float4 w0 = Wl[0 * 256 + c];
        float4 w1 = Wl[1 * 256 + c];
        float4 w2 = Wl[2 * 256 + c];
        float4 w3 = Wl[3 * 256 + c];
        a0 += (double)v.x * w0.x + (double)v.y * w0.y + (double)v.z * w0.z + (double)v.w * w0.w;
        a1 += (double)v.x * w1.x + (double)v.y * w1.y + (double)v.z * w1.z + (double)v.w * w1.w;
        a2 += (double)v.x * w2.x + (double)v.y * w2.y + (double)v.z * w2.z + (double)v.w * w2.w;
        a3 += (double)v.x * w3.x + (double)v.y * w3.y + (double)v.z * w3.z + (double)v.w * w3.w;
    }
#pragma unroll
    for (int off = 32; off > 0; off >>= 1) {
        a0 += __shfl_xor(a0, off);
        a1 += __shfl_xor(a1, off);
        a2 += __shfl_xor(a2, off);
        a3 += __shfl_xor(a3, off);
    }
    if (lane == 0) {
        // fp32 logits, like the reference's fp32 einsum output
        float f0 = (float)(a0 + (double)bias[0]);
        float f1 = (float)(a1 + (double)bias[1]);
        float f2 = (float)(a2 + (double)bias[2]);
        float f3 = (float)(a3 + (double)bias[3]);
        double m = fmax(fmax((double)f0, (double)f1), fmax((double)f2, (double)f3));
        double e0 = exp((double)f0 - m);
        double e1 = exp((double)f1 - m);
        double e2 = exp((double)f2 - m);
        double e3 = exp((double)f3 - m);
        double s = e0 + e1 + e2 + e3;
        float4 p;
        p.x = (float)(e0 / s);
        p.y = (float)(e1 / s);
        p.z = (float)(e2 / s);
        p.w = (float)(e3 / s);
        ((float4*)probs)[tok] = p;
    }
}

// ---------------------------------------------------------------------------
// select: exact top-CAP per batch row via 44-bit radix select.
// key = (monotone_uint(fp32 prob) << 12) | (4095 - n)  -> distinct keys,
// lower index wins ties (matches lax.top_k). masked tokens -> -inf key.
// One block per batch row; marks union into sel[] (same-value stores).
// ---------------------------------------------------------------------------
__global__ __launch_bounds__(256) void select_kernel(const float* __restrict__ probs,
                                                     const int* __restrict__ mask,
                                                     int* __restrict__ sel,
                                                     int j) {
    __shared__ unsigned long long keys[NTOK];   // 32 KB
    __shared__ unsigned int hist[256];
    __shared__ unsigned int scan[256];
    __shared__ unsigned long long pref_sh;
    __shared__ unsigned int rem_sh;

    int b   = blockIdx.x;
    int tid = threadIdx.x;
    const unsigned NEG_INF_KEY = 0x007FFFFFu;   // monotone map of -inf (0xFF800000 -> ~bits)

    for (int i = tid; i < NTOK; i += 256) {
        unsigned u;
        if (mask[i] != -1) {
            u = NEG_INF_KEY;
        } else {
            unsigned bits = __float_as_uint(probs[(b * NTOK + i) * NE + j]);
            u = (bits & 0x80000000u) ? ~bits : (bits | 0x80000000u);
        }
        keys[i] = ((unsigned long long)u << 12) | (unsigned)(NTOK - 1 - i);
    }
    if (tid == 0) { pref_sh = 0; rem_sh = CAP; }
    __syncthreads();

    for (int shift = 40; shift >= 0; shift -= 8) {
        hist[tid] = 0;
        __syncthreads();
        unsigned long long pref = pref_sh;
        unsigned rem = rem_sh;
        for (int i = tid; i < NTOK; i += 256) {
            unsigned long long K = keys[i];
            if ((K >> (shift + 8)) == pref)
                atomicAdd(&hist[(unsigned)(K >> shift) & 255u], 1u);
        }
        __syncthreads();
        // inclusive suffix scan: scan[d] = sum_{d' >= d} hist[d']
        scan[tid] = hist[tid];
        __syncthreads();
        for (int off = 1; off < 256; off <<= 1) {
            unsigned add = (tid + off < 256) ? scan[tid + off] : 0u;
            __syncthreads();
            scan[tid] += add;
            __syncthreads();
        }
        unsigned incl = scan[tid];
        unsigned excl = (tid < 255) ? scan[tid + 1] : 0u;
        if (excl < rem && rem <= incl) {   // exactly one tid fires
            pref_sh = (pref << 8) | (unsigned long long)tid;
            rem_sh  = rem - excl;
        }
        __syncthreads();
    }

    unsigned long long T = pref_sh;   // exact CAP-th largest key
    for (int i = tid; i < NTOK; i += 256) {
        if (keys[i] >= T) atomicOr(&sel[i], 1);
    }
}

// ---------------------------------------------------------------------------
// update: apply union -> mask = j, clear sel for next round
// ---------------------------------------------------------------------------
__global__ __launch_bounds__(256) void update_kernel(int* __restrict__ mask,
                                                     int* __restrict__ sel,
                                                     int j) {
    int i = blockIdx.x * 256 + threadIdx.x;
    if (i < NTOK) {
        if (sel[i]) { mask[i] = j; sel[i] = 0; }
    }
}

// ---------------------------------------------------------------------------
// final: out[0 .. B*N) = (float)mask (broadcast rows, -1 -> 0)
//        out[B*N .. 2*B*N) = probs gathered at mask
// ---------------------------------------------------------------------------
__global__ __launch_bounds__(256) void final_kernel(const float* __restrict__ probs,
                                                    const int* __restrict__ mask,
                                                    float* __restrict__ out) {
    int i = blockIdx.x * 256 + threadIdx.x;   // 0 .. B*N-1
    if (i < NB * NTOK) {
        int n = i & (NTOK - 1);
        int m = mask[n];
        if (m < 0) m = 0;
        out[i] = (float)m;
        out[NB * NTOK + i] = probs[i * NE + m];
    }
}

extern "C" void kernel_launch(void* const* d_in, const int* in_sizes, int n_in,
                              void* d_out, int out_size, void* d_ws, size_t ws_size,
                              hipStream_t stream) {
    const float* tokens = (const float*)d_in[0];   // [8, 4096, 1024] fp32
    const float* W      = (const float*)d_in[1];   // [4, 1024] fp32
    const float* bias   = (const float*)d_in[2];   // [4] fp32
    float* out = (float*)d_out;                    // [2 * 8 * 4096] fp32

    float* probs = (float*)d_ws;                                           // 512 KB
    int*   mask  = (int*)((char*)d_ws + (size_t)NB * NTOK * NE * sizeof(float));
    int*   sel   = mask + NTOK;

    init_kernel<<<(NTOK + 255) / 256, 256, 0, stream>>>(mask, sel);
    probs_kernel<<<(NB * NTOK) / 4, 256, 0, stream>>>(tokens, W, bias, probs);
    for (int j = NE - 1; j >= 0; j--) {
        // capacity = floor(0.25 * N) = 1024 > 0 for every expert
        select_kernel<<<NB, 256, 0, stream>>>(probs, mask, sel, j);
        update_kernel<<<(NTOK + 255) / 256, 256, 0, stream>>>(mask, sel, j);
    }
    final_kernel<<<(NB * NTOK + 255) / 256, 256, 0, stream>>>(probs, mask, out);
}

// Round 2
// 208.804 us; speedup vs baseline: 1.5973x; 1.5973x over previous
//
#include <hip/hip_runtime.h>
#include <math.h>

#define DIM 1024
#define NE 4
#define NTOK 4096
#define NB 8
#define CAP 1024   // floor(0.25 * 4096)

// ===========================================================================
// probs: one wave per token. logits accumulated in double (correctly-rounded
// fp32), softmax in double, rounded once to fp32. probs layout: [(b*N+n)*4+e]
// (unchanged from round 1 — token_mask matched exactly with these numerics)
// ===========================================================================
__global__ __launch_bounds__(256) void probs_kernel(const float* __restrict__ tokens,
                                                    const float* __restrict__ W,
                                                    const float* __restrict__ bias,
                                                    float* __restrict__ probs) {
    __shared__ float4 Wl[NE * 256];   // 16 KB
    int tid = threadIdx.x;
    const float4* W4 = (const float4*)W;
    for (int i = tid; i < NE * 256; i += 256) Wl[i] = W4[i];
    __syncthreads();

    int wave = tid >> 6, lane = tid & 63;
    long tok = (long)blockIdx.x * 4 + wave;            // 0 .. 32767
    const float4* t4 = (const float4*)(tokens + tok * DIM);

    double a0 = 0, a1 = 0, a2 = 0, a3 = 0;
#pragma unroll
    for (int kk = 0; kk < 4; kk++) {
        int c = lane + 64 * kk;                         // coalesced float4
        float4 v  = t4[c];
        float4 w0 = Wl[0 * 256 + c];
        float4 w1 = Wl[1 * 256 + c];
        float4 w2 = Wl[2 * 256 + c];
        float4 w3 = Wl[3 * 256 + c];
        a0 += (double)v.x * w0.x + (double)v.y * w0.y + (double)v.z * w0.z + (double)v.w * w0.w;
        a1 += (double)v.x * w1.x + (double)v.y * w1.y + (double)v.z * w1.z + (double)v.w * w1.w;
        a2 += (double)v.x * w2.x + (double)v.y * w2.y + (double)v.z * w2.z + (double)v.w * w2.w;
        a3 += (double)v.x * w3.x + (double)v.y * w3.y + (double)v.z * w3.z + (double)v.w * w3.w;
    }
#pragma unroll
    for (int off = 32; off > 0; off >>= 1) {
        a0 += __shfl_xor(a0, off);
        a1 += __shfl_xor(a1, off);
        a2 += __shfl_xor(a2, off);
        a3 += __shfl_xor(a3, off);
    }
    if (lane == 0) {
        float f0 = (float)(a0 + (double)bias[0]);
        float f1 = (float)(a1 + (double)bias[1]);
        float f2 = (float)(a2 + (double)bias[2]);
        float f3 = (float)(a3 + (double)bias[3]);
        double m = fmax(fmax((double)f0, (double)f1), fmax((double)f2, (double)f3));
        double e0 = exp((double)f0 - m);
        double e1 = exp((double)f1 - m);
        double e2 = exp((double)f2 - m);
        double e3 = exp((double)f3 - m);
        double s = e0 + e1 + e2 + e3;
        float4 p;
        p.x = (float)(e0 / s);
        p.y = (float)(e1 / s);
        p.z = (float)(e2 / s);
        p.w = (float)(e3 / s);
        ((float4*)probs)[tok] = p;
    }
}

// ===========================================================================
// helpers (1024-thread block)
// ===========================================================================

// exclusive prefix sum over per-thread values; wl must hold >= 17 unsigneds.
// Leaves a trailing __syncthreads so wl can be reused immediately after.
__device__ __forceinline__ unsigned block_exscan_1024(unsigned v, unsigned* wl,
                                                      int tid, unsigned* total) {
    int lane = tid & 63, w = tid >> 6;    // 16 waves
    unsigned s = v;
#pragma unroll
    for (int off = 1; off < 64; off <<= 1) {
        unsigned t = __shfl_up(s, off);
        if (lane >= off) s += t;
    }
    if (lane == 63) wl[w] = s;            // wave totals
    __syncthreads();
    if (tid < 64) {                       // whole wave 0 participates
        unsigned x = (tid < 16) ? wl[tid] : 0u;
#pragma unroll
        for (int off = 1; off < 16; off <<= 1) {
            unsigned t = __shfl_up(x, off);
            if (lane >= off) x += t;
        }
        if (tid < 16) wl[tid] = x;        // inclusive wave-offset scan
    }
    __syncthreads();
    unsigned waveoff = (w == 0) ? 0u : wl[w - 1];
    unsigned tot = wl[15];
    __syncthreads();                      // protect wl reuse across calls
    if (total) *total = tot;
    return waveoff + (s - v);
}

// Exact CAP-th-largest selection threshold over keys[0..4095] (LDS), MSB-first
// 8-bit radix. Returns v* (the cap-th largest key value, duplicates counted)
// and rem = number of keys == v* to accept (by ascending index).
__device__ __forceinline__ void radix_select_1024(const unsigned* keys, unsigned cap,
                                                  unsigned* hist, unsigned* scanb,
                                                  unsigned* bcast, int tid,
                                                  unsigned* v_out, unsigned* rem_out) {
    if (tid == 0) { bcast[0] = 0u; bcast[1] = cap; }
    __syncthreads();
#pragma unroll
    for (int shift = 24; shift >= 0; shift -= 8) {
        if (tid < 256) hist[tid] = 0u;
        __syncthreads();
        unsigned pref = bcast[0], rem = bcast[1];
        bool all = (shift == 24);
#pragma unroll
        for (int k = 0; k < 4; k++) {
            unsigned K = keys[tid + k * 1024];
            if (all || (K >> (shift + 8)) == pref)
                atomicAdd(&hist[(K >> shift) & 255u], 1u);
        }
        __syncthreads();
        // wave 0: inclusive suffix scan of 256 bins via shuffles
        if (tid < 64) {
            unsigned h0 = hist[4 * tid], h1 = hist[4 * tid + 1];
            unsigned h2 = hist[4 * tid + 2], h3 = hist[4 * tid + 3];
            unsigned s3 = h3, s2 = h2 + s3, s1 = h1 + s2, s0 = h0 + s1;
            unsigned t = s0, s = t;
#pragma unroll
            for (int off = 1; off < 64; off <<= 1) {
                unsigned o = __shfl_down(s, off);
                if (tid + off < 64) s += o;
            }
            unsigned E = s - t;           // sum over lanes > tid
            scanb[4 * tid]     = E + s0;
            scanb[4 * tid + 1] = E + s1;
            scanb[4 * tid + 2] = E + s2;
            scanb[4 * tid + 3] = E + s3;
        }
        __syncthreads();
        if (tid < 256) {
            unsigned incl = scanb[tid];
            unsigned excl = (tid < 255) ? scanb[tid + 1] : 0u;
            if (excl < rem && rem <= incl) {     // exactly one digit fires
                bcast[0] = (pref << 8) | (unsigned)tid;
                bcast[1] = rem - excl;
            }
        }
        __syncthreads();
    }
    *v_out = bcast[0];
    *rem_out = bcast[1];
}

__device__ __forceinline__ unsigned mono_key(float p) {
    unsigned bits = __float_as_uint(p);
    return (bits & 0x80000000u) ? ~bits : (bits | 0x80000000u);
}

// ===========================================================================
// select3: round j=3 (no mask yet). One block per batch row. Exact top-CAP
// (lax.top_k tie-break: lowest index wins among equal values) -> bitmap.
// ===========================================================================
__global__ __launch_bounds__(1024) void select3_kernel(const float* __restrict__ probs,
                                                       unsigned* __restrict__ selbits) {
    __shared__ unsigned keys[NTOK];           // 16 KB
    __shared__ unsigned hist[256], scanb[256], bcast[2];
    __shared__ unsigned bitmap[128];
    __shared__ unsigned wl[17];
    int b = blockIdx.x, tid = threadIdx.x;

#pragma unroll
    for (int k = 0; k < 4; k++) {
        int i = tid + k * 1024;
        keys[i] = mono_key(probs[((size_t)b * NTOK + i) * NE + 3]);
    }
    if (tid < 128) bitmap[tid] = 0u;
    __syncthreads();

    unsigned vstar, rem;
    radix_select_1024(keys, CAP, hist, scanb, bcast, tid, &vstar, &rem);

    // tie rank (ascending index): thread owns sequential indices 4t..4t+3
    unsigned loc[4], v = 0;
#pragma unroll
    for (int k = 0; k < 4; k++) { loc[k] = (keys[4 * tid + k] == vstar); v += loc[k]; }
    unsigned tot;
    unsigned ex = block_exscan_1024(v, wl, tid, &tot);
#pragma unroll
    for (int k = 0; k < 4; k++) {
        int i = 4 * tid + k;
        bool sel = (keys[i] > vstar) || (loc[k] && ex < rem);
        ex += loc[k];
        if (sel) atomicOr(&bitmap[i >> 5], 1u << (i & 31));
    }
    __syncthreads();
    if (tid < 128) selbits[b * 128 + tid] = bitmap[tid];
}

// ===========================================================================
// rest: single block. Union round-3 bitmaps -> mask=3; then rounds j=2,1,0.
// Mask is shared across rows => unmasked count U is row-independent:
//   U <= CAP : every row selects ALL unmasked + (CAP-U) lowest-index masked
//              (-inf ties, lax.top_k stable order) -> one block scan, no topk.
//   U >  CAP : general fallback: per-row radix select among unmasked, union.
// Writes final token_mask (with -1 -> 0).
// ===========================================================================
__global__ __launch_bounds__(1024) void rest_kernel(const float* __restrict__ probs,
                                                    const unsigned* __restrict__ selbits,
                                                    int* __restrict__ finalmask) {
    __shared__ unsigned keys[NTOK];           // slow path scratch
    __shared__ int maskv[NTOK];               // 16 KB
    __shared__ unsigned hist[256], scanb[256], bcast[2];
    __shared__ unsigned bitmap[128];
    __shared__ unsigned wl[17];
    int tid = threadIdx.x;

    if (tid < 128) {
        unsigned u = 0;
#pragma unroll
        for (int b = 0; b < NB; b++) u |= selbits[b * 128 + tid];
        bitmap[tid] = u;
    }
    __syncthreads();
#pragma unroll
    for (int k = 0; k < 4; k++) {
        int i = tid + k * 1024;
        maskv[i] = ((bitmap[i >> 5] >> (i & 31)) & 1u) ? 3 : -1;
    }
    __syncthreads();

    for (int j = 2; j >= 0; j--) {
        // rank of masked tokens by ascending index + total masked count
        unsigned loc[4], v = 0;
#pragma unroll
        for (int k = 0; k < 4; k++) { loc[k] = (maskv[4 * tid + k] != -1); v += loc[k]; }
        unsigned M;
        unsigned ex = block_exscan_1024(v, wl, tid, &M);
        unsigned U = NTOK - M;

        if (U <= CAP) {
            unsigned need = CAP - U;          // -inf ties to take (lowest index)
#pragma unroll
            for (int k = 0; k < 4; k++) {
                int i = 4 * tid + k;
                bool sel = (!loc[k]) || (ex < need);
                ex += loc[k];
                if (sel) maskv[i] = j;        // thread owns its 4 indices
            }
            __syncthreads();
        } else {
            // general fallback (not expected on this data)
            if (tid < 128) bitmap[tid] = 0u;
            __syncthreads();
            for (int b = 0; b < NB; b++) {
#pragma unroll
                for (int k = 0; k < 4; k++) {
                    int i = tid + k * 1024;
                    keys[i] = (maskv[i] != -1)
                                  ? 0u   // below every real prob key (>= 0x80000000)
                                  : mono_key(probs[((size_t)b * NTOK + i) * NE + j]);
                }
                __syncthreads();
                unsigned vstar, rem;
                radix_select_1024(keys, CAP, hist, scanb, bcast, tid, &vstar, &rem);
                unsigned l2[4], v2 = 0;
#pragma unroll
                for (int k = 0; k < 4; k++) { l2[k] = (keys[4 * tid + k] == vstar); v2 += l2[k]; }
                unsigned tot2;
                unsigned ex2 = block_exscan_1024(v2, wl, tid, &tot2);
#pragma unroll
                for (int k = 0; k < 4; k++) {
                    int i = 4 * tid + k;
                    bool sel = (keys[i] > vstar) || (l2[k] && ex2 < rem);
                    ex2 += l2[k];
                    if (sel) atomicOr(&bitmap[i >> 5], 1u << (i & 31));
                }
                __syncthreads();
            }
#pragma unroll
            for (int k = 0; k < 4; k++) {
                int i = 4 * tid + k;
                if ((bitmap[i >> 5] >> (i & 31)) & 1u) maskv[i] = j;
            }
            __syncthreads();
        }
    }

#pragma unroll
    for (int k = 0; k < 4; k++) {
        int i = tid + k * 1024;
        int m = maskv[i];
        finalmask[i] = (m < 0) ? 0 : m;
    }
}

// ===========================================================================
// final: out[0..B*N) = (float)mask broadcast; out[B*N..2*B*N) = gathered probs
// ===========================================================================
__global__ __launch_bounds__(256) void final_kernel(const float* __restrict__ probs,
                                                    const int* __restrict__ fm,
                                                    float* __restrict__ out) {
    int i = blockIdx.x * 256 + threadIdx.x;   // 0 .. B*N-1
    int n = i & (NTOK - 1);
    int m = fm[n];
    out[i] = (float)m;
    out[NB * NTOK + i] = probs[(size_t)i * NE + m];
}

extern "C" void kernel_launch(void* const* d_in, const int* in_sizes, int n_in,
                              void* d_out, int out_size, void* d_ws, size_t ws_size,
                              hipStream_t stream) {
    const float* tokens = (const float*)d_in[0];   // [8, 4096, 1024] fp32
    const float* W      = (const float*)d_in[1];   // [4, 1024] fp32
    const float* bias   = (const float*)d_in[2];   // [4] fp32
    float* out = (float*)d_out;                    // [2 * 8 * 4096] fp32

    float*    probs   = (float*)d_ws;                                   // 512 KB
    unsigned* selbits = (unsigned*)((char*)d_ws + (size_t)NB * NTOK * NE * sizeof(float));
    int*      fmask   = (int*)(selbits + NB * 128);                     // 16 KB

    probs_kernel<<<(NB * NTOK) / 4, 256, 0, stream>>>(tokens, W, bias, probs);
    select3_kernel<<<NB, 1024, 0, stream>>>(probs, selbits);
    rest_kernel<<<1, 1024, 0, stream>>>(probs, selbits, fmask);
    final_kernel<<<(NB * NTOK) / 256, 256, 0, stream>>>(probs, fmask, out);
}